// Round 1
// baseline (693.766 us; speedup 1.0000x reference)
//
#include <hip/hip_runtime.h>

#define NH 10
#define NB 8        // batches
#define NC 8        // channels
#define NT 16384    // targets
#define NS 4096     // sources
#define EPSW 1e-10f
#define FINF 3.402823466e+38f

// One wave (64 lanes) per target. 4 waves per block -> 4 targets/block.
__global__ __launch_bounds__(256) void knn_interp_kernel(
    const float* __restrict__ x,    // [NB, NS, NC]
    const float* __restrict__ rel,  // [NT, NS, 2]
    float* __restrict__ out)        // [NB, NT, NC]
{
    const int lane = threadIdx.x & 63;
    const int wave = threadIdx.x >> 6;
    const int t = blockIdx.x * 4 + wave;

    // ---- per-lane top-NH (sorted ascending by d2), all static-indexed ----
    float v[NH];
    int   id[NH];
#pragma unroll
    for (int k = 0; k < NH; ++k) { v[k] = FINF; id[k] = 0x7FFFFFFF; }

    const float4* relrow = (const float4*)(rel + (size_t)t * (NS * 2));

    // 4096 sources / 2 per float4 / 64 lanes = 32 iterations
#pragma unroll 4
    for (int j = 0; j < (NS / 2 / 64); ++j) {
        const int f4i = j * 64 + lane;
        float4 f = relrow[f4i];
        const int s0 = f4i * 2;

        float d2a = f.x * f.x + f.y * f.y;
        float d2b = f.z * f.z + f.w * f.w;

        if (d2a < v[NH - 1]) {
            float tv = d2a; int ti = s0;
#pragma unroll
            for (int k = 0; k < NH; ++k) {
                bool c = tv < v[k];
                float nv = c ? tv : v[k];
                float mv = c ? v[k] : tv;
                int   ni = c ? ti : id[k];
                int   mi = c ? id[k] : ti;
                v[k] = nv; id[k] = ni; tv = mv; ti = mi;
            }
        }
        if (d2b < v[NH - 1]) {
            float tv = d2b; int ti = s0 + 1;
#pragma unroll
            for (int k = 0; k < NH; ++k) {
                bool c = tv < v[k];
                float nv = c ? tv : v[k];
                float mv = c ? v[k] : tv;
                int   ni = c ? ti : id[k];
                int   mi = c ? id[k] : ti;
                v[k] = nv; id[k] = ni; tv = mv; ti = mi;
            }
        }
    }

    // ---- wave all-reduce: extract global top-NH, 1 round per neighbor ----
    // key = (d2 bits << 32) | src_idx ; d2 >= 0 so float bits are order-
    // preserving as u32; unique src_idx gives lower-index-first tie-break
    // (matches jax.lax.top_k).
    float rd[NH];
    int   ridx[NH];
#pragma unroll
    for (int r = 0; r < NH; ++r) {
        unsigned long long key =
            ((unsigned long long)__float_as_uint(v[0]) << 32) | (unsigned)id[0];
        unsigned long long m = key;
#pragma unroll
        for (int o = 32; o > 0; o >>= 1) {
            unsigned long long other = __shfl_xor(m, o, 64);
            m = (other < m) ? other : m;
        }
        rd[r]   = __uint_as_float((unsigned)(m >> 32));
        ridx[r] = (int)(unsigned)(m & 0xFFFFFFFFull);

        // the (unique) winning lane pops its head
        bool won = (key == m);
#pragma unroll
        for (int k = 0; k < NH - 1; ++k) {
            v[k]  = won ? v[k + 1]  : v[k];
            id[k] = won ? id[k + 1] : id[k];
        }
        v[NH - 1]  = won ? FINF : v[NH - 1];
        id[NH - 1] = won ? 0x7FFFFFFF : id[NH - 1];
    }

    // ---- weights (every lane computes all NH redundantly) ----
    float w[NH];
    float wsum = 0.f;
#pragma unroll
    for (int r = 0; r < NH; ++r) {
        float d = sqrtf(rd[r]);
        w[r] = 1.0f / (d + EPSW);
        wsum += w[r];
    }
    const float inv = 1.0f / wsum;

    // ---- gather + weighted sum: lane = b*8 + c covers all (b,c) pairs ----
    const int b = lane >> 3;
    const int c = lane & 7;
    const float* xb = x + ((size_t)b * NS) * NC + c;
    float acc = 0.f;
#pragma unroll
    for (int r = 0; r < NH; ++r) {
        acc += w[r] * xb[(size_t)ridx[r] * NC];
    }
    out[((size_t)b * NT + t) * NC + c] = acc * inv;
}

extern "C" void kernel_launch(void* const* d_in, const int* in_sizes, int n_in,
                              void* d_out, int out_size, void* d_ws, size_t ws_size,
                              hipStream_t stream) {
    const float* x   = (const float*)d_in[0];
    const float* rel = (const float*)d_in[1];
    float* out = (float*)d_out;

    dim3 grid(NT / 4);   // 4 targets (waves) per 256-thread block
    dim3 block(256);
    knn_interp_kernel<<<grid, block, 0, stream>>>(x, rel, out);
}

// Round 3
// 662.091 us; speedup vs baseline: 1.0478x; 1.0478x over previous
//
#include <hip/hip_runtime.h>

#define NH 10
#define NB 8        // batches
#define NC 8        // channels
#define NT 16384    // targets
#define NS 4096     // sources
#define EPSW 1e-10f
#define FINF 3.402823466e+38f

typedef float float4n __attribute__((ext_vector_type(4)));  // native vec for nontemporal builtin

// Branch-free sorted insert of (t, ti) into ascending (v[], id[]).
// Value chain: v'[k] = med3(t, v[k-1], v[k])  (1 inst/stage).
// Index chain: id'[k] = c[k-1] ? id[k-1] : (c[k] ? ti : id[k])  (2 cndmask).
// Strict '<' keeps earlier-arriving (lower source idx) first on bit-equal d2,
// matching jax top_k lower-index-first within a lane.
__device__ __forceinline__ void insert1(float t, int ti, float v[NH], int id[NH]) {
    bool c[NH];
#pragma unroll
    for (int k = 0; k < NH; ++k) c[k] = t < v[k];
    float nv[NH]; int ni[NH];
    nv[0] = c[0] ? t : v[0];
    ni[0] = c[0] ? ti : id[0];
#pragma unroll
    for (int k = 1; k < NH; ++k) {
        nv[k] = __builtin_amdgcn_fmed3f(t, v[k - 1], v[k]);
        ni[k] = c[k - 1] ? id[k - 1] : (c[k] ? ti : id[k]);
    }
#pragma unroll
    for (int k = 0; k < NH; ++k) { v[k] = nv[k]; id[k] = ni[k]; }
}

// One wave (64 lanes) per target, 4 waves per 256-thread block.
__global__ __launch_bounds__(256) void knn_interp_kernel(
    const float* __restrict__ x,    // [NB, NS, NC]
    const float* __restrict__ rel,  // [NT, NS, 2]
    float* __restrict__ out)        // [NB, NT, NC]
{
    const int lane = threadIdx.x & 63;
    const int wave = threadIdx.x >> 6;
    const int t = blockIdx.x * 4 + wave;

    float v[NH];
    int   id[NH];
#pragma unroll
    for (int k = 0; k < NH; ++k) { v[k] = FINF; id[k] = 0x7FFFFFFF; }

    const float4n* relrow = (const float4n*)(rel + (size_t)t * (NS * 2));

    // 2048 float4s per target / 64 lanes = 32 per lane; chunks of 4, 8 chunks.
    // Chunk j covers f4 indices j*256 + u*64 + lane (coalesced per u).
    float4n cur[4];
#pragma unroll
    for (int u = 0; u < 4; ++u)
        cur[u] = __builtin_nontemporal_load(&relrow[u * 64 + lane]);

#pragma unroll 1
    for (int j = 0; j < 7; ++j) {
        float4n nxt[4];
#pragma unroll
        for (int u = 0; u < 4; ++u)
            nxt[u] = __builtin_nontemporal_load(&relrow[(j + 1) * 256 + u * 64 + lane]);
#pragma unroll
        for (int u = 0; u < 4; ++u) {
            const int f4i = j * 256 + u * 64 + lane;
            float d2a = cur[u].x * cur[u].x + cur[u].y * cur[u].y;
            float d2b = cur[u].z * cur[u].z + cur[u].w * cur[u].w;
            insert1(d2a, f4i * 2,     v, id);
            insert1(d2b, f4i * 2 + 1, v, id);
        }
#pragma unroll
        for (int u = 0; u < 4; ++u) cur[u] = nxt[u];
    }
    // epilogue chunk j=7
#pragma unroll
    for (int u = 0; u < 4; ++u) {
        const int f4i = 7 * 256 + u * 64 + lane;
        float d2a = cur[u].x * cur[u].x + cur[u].y * cur[u].y;
        float d2b = cur[u].z * cur[u].z + cur[u].w * cur[u].w;
        insert1(d2a, f4i * 2,     v, id);
        insert1(d2b, f4i * 2 + 1, v, id);
    }

    // ---- wave all-reduce: global top-NH via u64 (d2bits<<32 | idx) keys ----
    float rd[NH];
    int   ridx[NH];
#pragma unroll
    for (int r = 0; r < NH; ++r) {
        unsigned long long key =
            ((unsigned long long)__float_as_uint(v[0]) << 32) | (unsigned)id[0];
        unsigned long long m = key;
#pragma unroll
        for (int o = 32; o > 0; o >>= 1) {
            unsigned long long other = __shfl_xor(m, o, 64);
            m = (other < m) ? other : m;
        }
        rd[r]   = __uint_as_float((unsigned)(m >> 32));
        ridx[r] = (int)(unsigned)(m & 0xFFFFFFFFull);

        bool won = (key == m);  // unique idx -> exactly one winner
#pragma unroll
        for (int k = 0; k < NH - 1; ++k) {
            v[k]  = won ? v[k + 1]  : v[k];
            id[k] = won ? id[k + 1] : id[k];
        }
        v[NH - 1]  = won ? FINF : v[NH - 1];
        id[NH - 1] = won ? 0x7FFFFFFF : id[NH - 1];
    }

    // ---- weights ----
    float w[NH];
    float wsum = 0.f;
#pragma unroll
    for (int r = 0; r < NH; ++r) {
        float d = sqrtf(rd[r]);
        w[r] = 1.0f / (d + EPSW);
        wsum += w[r];
    }
    const float inv = 1.0f / wsum;

    // ---- gather + weighted sum: lane = b*8 + c covers all (b,c) pairs ----
    const int b = lane >> 3;
    const int c = lane & 7;
    const float* xb = x + ((size_t)b * NS) * NC + c;
    float acc = 0.f;
#pragma unroll
    for (int r = 0; r < NH; ++r) {
        acc += w[r] * xb[(size_t)ridx[r] * NC];
    }
    out[((size_t)b * NT + t) * NC + c] = acc * inv;
}

extern "C" void kernel_launch(void* const* d_in, const int* in_sizes, int n_in,
                              void* d_out, int out_size, void* d_ws, size_t ws_size,
                              hipStream_t stream) {
    const float* x   = (const float*)d_in[0];
    const float* rel = (const float*)d_in[1];
    float* out = (float*)d_out;

    dim3 grid(NT / 4);   // 4 targets (waves) per 256-thread block
    dim3 block(256);
    knn_interp_kernel<<<grid, block, 0, stream>>>(x, rel, out);
}